// Round 17
// baseline (67.731 us; speedup 1.0000x reference)
//
#include <hip/hip_runtime.h>
#include <hip/hip_bf16.h>
#include <math.h>

#define BATCH 512
#define FEAT  256
#define NCLS  100000
#define SCALE_ 32.0f
#define M0_    0.5f
#define MMIN_  0.25f

#define BN 64                        // classes per tile
#define NT64 1563                    // ceil(100000/64); tile 1562 is half (32 rows)
#define NSLOTS 256                   // class-tile slots (stride)
#define NPART 256                    // partial slots per sample
#define K4CHUNK 16
#define NK4 (NPART / K4CHUNK)        // 16

#define LOG2E_ 1.44269504088896f
#define K2C_   (SCALE_ * LOG2E_)     // 46.166...; fixed softmax max (log2 domain)

typedef unsigned short u16;
typedef short s16x8 __attribute__((ext_vector_type(8)));
typedef float f32x4 __attribute__((ext_vector_type(4)));

// ---- static device scratch ----
__device__ u16   g_fbf16[BATCH * FEAT];    // normalized features, bf16
__device__ float g_norms[BATCH];
__device__ float g_dot[BATCH];             // raw f32 feat . W[label]
__device__ float g_wn2[BATCH];             // ||W[label]||^2 (f32)
__device__ float g_psum[NPART * BATCH];    // fixed-max partial sums
__device__ float g_qs[NK4 * BATCH];

__device__ __forceinline__ u16 f2b(float x) {
  union { float f; unsigned u; } v; v.f = x;
  unsigned r = v.u + 0x7FFFu + ((v.u >> 16) & 1u);   // RNE
  return (u16)(r >> 16);
}

// packed f32x2 -> bf16x2 (lo = a, hi = b)
__device__ __forceinline__ unsigned pkbf16(float a, float b) {
  unsigned r;
  asm("v_cvt_pk_bf16_f32 %0, %1, %2" : "=v"(r) : "v"(a), "v"(b));
  return r;
}

__device__ __forceinline__ float ex2(float x) {
  return __builtin_amdgcn_exp2f(x);
}

// K12 (merged k1a + k2c, data-independent halves):
// blocks 0..127: per-row feature norm -> NORMALIZED bf16 row + g_norms.
// blocks 128..255: raw f32 dot(feat_i, W[label_i]) and ||W[label_i]||^2;
//   label width (int32 vs int64) detected locally per wave.
__global__ void k12(const float* __restrict__ feat, const float* __restrict__ wmat,
                    const void* __restrict__ labels) {
  int b = blockIdx.x;
  int wid = threadIdx.x >> 6, lane = threadIdx.x & 63;
  if (b < 128) {
    int row = b * 4 + wid;
    float4 f = ((const float4*)(feat + row * FEAT))[lane];
    float ss = f.x * f.x + f.y * f.y + f.z * f.z + f.w * f.w;
    #pragma unroll
    for (int d = 1; d < 64; d <<= 1) ss += __shfl_xor(ss, d, 64);
    float nrm = sqrtf(ss);
    float inv = 1.0f / fmaxf(nrm, 1e-12f);
    ushort4 h;
    h.x = f2b(f.x * inv); h.y = f2b(f.y * inv);
    h.z = f2b(f.z * inv); h.w = f2b(f.w * inv);
    ((ushort4*)(g_fbf16 + row * FEAT))[lane] = h;
    if (lane == 0) g_norms[row] = nrm;
  } else {
    int i = (b - 128) * 4 + wid;
    const int* labw = (const int*)labels;
    int odd = 0;
    #pragma unroll
    for (int k = 0; k < 4; ++k) odd |= labw[2 * (k * 64 + lane) + 1];
    unsigned long long bl = __ballot(odd != 0);
    long long lab;
    if (bl != 0ULL) lab = (long long)((const int*)labels)[i];
    else            lab = ((const long long*)labels)[i];
    float4 a = ((const float4*)(feat + i * FEAT))[lane];
    float4 w = ((const float4*)(wmat + (size_t)lab * FEAT))[lane];
    float d  = a.x * w.x + a.y * w.y + a.z * w.z + a.w * w.w;
    float bb = w.x * w.x + w.y * w.y + w.z * w.z + w.w * w.w;
    #pragma unroll
    for (int t = 1; t < 64; t <<= 1) {
      d  += __shfl_xor(d, t, 64);
      bb += __shfl_xor(bb, t, 64);
    }
    if (lane == 0) { g_dot[i] = d; g_wn2[i] = bb; }
  }
}

// K3 (fused): R16 structure with BN=64 (iters 13 -> 6-7, barriers halved,
// 4 phases per barrier window). 512 blocks x 256 threads (4 waves), m=4
// (fr[4][8] = 128 VGPR), 2x32 KB LDS dbuf -> 2 blocks/CU. bid = sh*256 +
// nslot; sh-pairs 256 apart dedupe the W read (FETCH ~51 MB, R12/R16
// evidence). Staging: two 32-row chunk pairs per tile reusing transient
// v_[8]; split-FINISH placement keeps global-load-to-use >= 1 phase (T14).
// T5 setprio around MFMA. FIXED-MAX softmax in exp2 domain: plain sums.
// Edge: tile 1562 covers classes 99968..100031 -> rows 32..63 OOB; LOADC
// clamps the row, epilogue masks terms (one block, one iter).

#define LOADC(TILE, RB) do {                                                \
    rowL_ = tid >> 4;                                                       \
    int r0_ = (TILE) * BN + (RB) + rowL_;                                   \
    int r1_ = r0_ + 16;                                                     \
    r0_ = r0_ < NCLS ? r0_ : NCLS - 1;                                      \
    r1_ = r1_ < NCLS ? r1_ : NCLS - 1;                                      \
    const float4* s0_ = (const float4*)(wmat + (size_t)r0_ * FEAT + (tid & 15) * 16); \
    const float4* s1_ = (const float4*)(wmat + (size_t)r1_ * FEAT + (tid & 15) * 16); \
    v_[0] = s0_[0]; v_[1] = s0_[1]; v_[2] = s0_[2]; v_[3] = s0_[3];         \
    v_[4] = s1_[0]; v_[5] = s1_[1]; v_[6] = s1_[2]; v_[7] = s1_[3];         \
  } while (0)

#define FINHALF(NB, G, ROW) do {                                            \
    float ss_ = 0.0f;                                                       \
    _Pragma("unroll")                                                       \
    for (int k_ = 0; k_ < 4; ++k_) {                                        \
      float4 vv_ = v_[(G) * 4 + k_];                                        \
      ss_ += vv_.x * vv_.x + vv_.y * vv_.y + vv_.z * vv_.z + vv_.w * vv_.w; \
    }                                                                       \
    ss_ += __shfl_xor(ss_, 1, 64);                                          \
    ss_ += __shfl_xor(ss_, 2, 64);                                          \
    ss_ += __shfl_xor(ss_, 4, 64);                                          \
    ss_ += __shfl_xor(ss_, 8, 64);                                          \
    float inv_ = 1.0f / fmaxf(sqrtf(ss_), 1e-12f);                          \
    u16* dst_ = &Ws[NB][0] + (ROW) * FEAT;                                  \
    _Pragma("unroll")                                                       \
    for (int k_ = 0; k_ < 2; ++k_) {                                        \
      int jj_ = (tid & 15) * 2 + k_;                                        \
      float4 va_ = v_[(G) * 4 + 2 * k_], vb_ = v_[(G) * 4 + 2 * k_ + 1];    \
      int4 w4_;                                                             \
      w4_.x = (int)pkbf16(va_.x * inv_, va_.y * inv_);                      \
      w4_.y = (int)pkbf16(va_.z * inv_, va_.w * inv_);                      \
      w4_.z = (int)pkbf16(vb_.x * inv_, vb_.y * inv_);                      \
      w4_.w = (int)pkbf16(vb_.z * inv_, vb_.w * inv_);                      \
      *(int4*)(dst_ + ((jj_ ^ ((ROW) & 7)) * 8)) = w4_;                     \
    }                                                                       \
  } while (0)

#define FINISHC(NB, RB) do {                                                \
    FINHALF(NB, 0, (RB) + rowL_);                                           \
    FINHALF(NB, 1, (RB) + 16 + rowL_);                                      \
  } while (0)

#define PHASE(p8) do {                                                      \
    f32x4 acc[4];                                                           \
    _Pragma("unroll")                                                       \
    for (int m = 0; m < 4; ++m) acc[m] = f32x4{0.0f, 0.0f, 0.0f, 0.0f};     \
    const u16* wb = &Ws[buf][0];                                            \
    const int row_ = (p8) * 16 + s;                                         \
    __builtin_amdgcn_s_setprio(1);                                          \
    _Pragma("unroll")                                                       \
    for (int c = 0; c < 8; ++c) {                                           \
      int cc = c * 4 + q;                                                   \
      s16x8 wf = *(const s16x8*)(wb + row_ * FEAT + (cc ^ (row_ & 7)) * 8); \
      _Pragma("unroll")                                                     \
      for (int m = 0; m < 4; ++m)                                           \
        acc[m] = __builtin_amdgcn_mfma_f32_16x16x32_bf16(wf, fr[m][c], acc[m], 0, 0, 0); \
    }                                                                       \
    __builtin_amdgcn_s_setprio(0);                                          \
    _Pragma("unroll")                                                       \
    for (int m = 0; m < 4; ++m) {                                           \
      float t0_ = ex2(fmaf(acc[m][0], K2C_, -K2C_));                        \
      float t1_ = ex2(fmaf(acc[m][1], K2C_, -K2C_));                        \
      float t2_ = ex2(fmaf(acc[m][2], K2C_, -K2C_));                        \
      float t3_ = ex2(fmaf(acc[m][3], K2C_, -K2C_));                        \
      if (edge) {                                                           \
        int cb_ = tile * BN + (p8) * 16 + q * 4;                            \
        if (cb_ + 0 >= NCLS) t0_ = 0.0f;                                    \
        if (cb_ + 1 >= NCLS) t1_ = 0.0f;                                    \
        if (cb_ + 2 >= NCLS) t2_ = 0.0f;                                    \
        if (cb_ + 3 >= NCLS) t3_ = 0.0f;                                    \
      }                                                                     \
      S[m] += (t0_ + t1_) + (t2_ + t3_);                                    \
    }                                                                       \
  } while (0)

__global__ __launch_bounds__(256, 1) void k3(const float* __restrict__ wmat) {
  __shared__ __align__(16) u16 Ws[2][BN * FEAT];   // 2 x 32 KB

  const int tid  = threadIdx.x;
  const int lane = tid & 63, wid = tid >> 6;       // 4 waves
  const int s = lane & 15, q = lane >> 4;
  const int bid = blockIdx.x;
  const int nslot = bid & 255;
  const int sh = bid >> 8;                         // sample half
  const int niter = ((NT64 - 1 - nslot) >> 8) + 1; // 7 (nslot<27) or 6

  int rowL_;
  float4 v_[8];

  // prologue: stage tile `nslot` into buf 0 (two chunk pairs)
  LOADC(nslot, 0);  FINISHC(0, 0);
  LOADC(nslot, 32); FINISHC(0, 32);

  // feature fragments (B-operand): 64 samples per wave, register-resident.
  s16x8 fr[4][8];
  {
    const int srow = sh * 256 + wid * 64;
    #pragma unroll
    for (int m = 0; m < 4; ++m)
      #pragma unroll
      for (int c = 0; c < 8; ++c)
        fr[m][c] = *(const s16x8*)(g_fbf16 + (srow + m * 16 + s) * FEAT + c * 32 + q * 8);
  }

  float S[4] = {0.0f, 0.0f, 0.0f, 0.0f};

  __syncthreads();

  int buf = 0;
  for (int t = 0; t < niter; ++t) {
    const bool last = (t + 1 == niter);
    const int tile = nslot + t * NSLOTS;
    const bool edge = (tile == NT64 - 1);
    const int ntile = nslot + (t + 1) * NSLOTS;

    if (!last) LOADC(ntile, 0);
    PHASE(0);
    if (!last) { FINISHC(buf ^ 1, 0); LOADC(ntile, 32); }
    PHASE(1);
    PHASE(2);
    if (!last) FINISHC(buf ^ 1, 32);
    PHASE(3);
    __syncthreads();
    buf ^= 1;
  }

  // cross-lane sum (once): combine the 4 q-groups per sample.
  #pragma unroll
  for (int m = 0; m < 4; ++m) {
    S[m] += __shfl_xor(S[m], 16, 64);
    S[m] += __shfl_xor(S[m], 32, 64);
  }

  if (lane < 16) {
    #pragma unroll
    for (int m = 0; m < 4; ++m) {
      int smp = sh * 256 + wid * 64 + m * 16 + lane;
      g_psum[nslot * BATCH + smp] = S[m];
    }
  }
}

// K4a: sum 16 of the 256 partial slots per sample per block (coalesced).
__global__ __launch_bounds__(512) void k4a() {
  int i = threadIdx.x;   // sample
  int b = blockIdx.x;    // chunk of partial slots
  float S = 0.0f;
  #pragma unroll 4
  for (int p = b * K4CHUNK; p < b * K4CHUNK + K4CHUNK; ++p)
    S += g_psum[p * BATCH + i];
  g_qs[b * BATCH + i] = S;
}

// K4b: chunk sum + margins (min/max of norms) + target-logit fixup +
// weighted mean. Fixed max K2C_ (log2 domain): lse = 32 + ln(S2).
__global__ void k4b(const float* __restrict__ wts, float* __restrict__ out) {
  int i = threadIdx.x;  // 512
  float S = 0.0f;
  #pragma unroll
  for (int t = 0; t < NK4; ++t) S += g_qs[t * BATCH + i];

  float n = g_norms[i];
  __shared__ float smin[512], smax[512];
  smin[i] = n; smax[i] = n;
  __syncthreads();
  for (int st = 256; st > 0; st >>= 1) {
    if (i < st) {
      smin[i] = fminf(smin[i], smin[i + st]);
      smax[i] = fmaxf(smax[i], smax[i + st]);
    }
    __syncthreads();
  }
  float lo = smin[0], hi = smax[0];
  float denom = fmaxf(hi - lo, 1e-8f);
  float mg = MMIN_ + (M0_ - MMIN_) * (n - lo) / denom;
  mg = fminf(fmaxf(mg, MMIN_), M0_);

  const float CLIP = 1.0f - 1e-7f;
  float wn = fmaxf(sqrtf(g_wn2[i]), 1e-12f);
  float ct = g_dot[i] / (fmaxf(n, 1e-12f) * wn);
  ct = fminf(fmaxf(ct, -CLIP), CLIP);

  float sint = sqrtf(fmaxf(0.0f, 1.0f - ct * ct));
  float cosm = ct * cosf(mg) - sint * sinf(mg);
  float b_old = K2C_ * ct;            // log2-domain target logits
  float b_new = K2C_ * cosm;
  float S2 = S - ex2(b_old - K2C_) + ex2(b_new - K2C_);
  float lse = 32.0f + logf(S2);       // natural-log lse (K2C_*ln2 = 32)
  float contrib = (lse - SCALE_ * cosm) * wts[i];
  __shared__ float sred[512];
  sred[i] = contrib;
  __syncthreads();
  for (int st = 256; st > 0; st >>= 1) {
    if (i < st) sred[i] += sred[i + st];
    __syncthreads();
  }
  if (i == 0) out[0] = sred[0] * (1.0f / (float)BATCH);
}

extern "C" void kernel_launch(void* const* d_in, const int* in_sizes, int n_in,
                              void* d_out, int out_size, void* d_ws, size_t ws_size,
                              hipStream_t stream) {
  const float* feat = (const float*)d_in[0];
  const float* wmat = (const float*)d_in[1];
  const float* wts  = (const float*)d_in[2];
  const void*  labs = d_in[3];
  float* out = (float*)d_out;

  hipLaunchKernelGGL(k12, dim3(256), dim3(256), 0, stream, feat, wmat, labs);
  hipLaunchKernelGGL(k3,  dim3(512), dim3(256), 0, stream, wmat);
  hipLaunchKernelGGL(k4a, dim3(NK4), dim3(512), 0, stream);
  hipLaunchKernelGGL(k4b, dim3(1), dim3(512), 0, stream, wts, out);
}

// Round 18
// 54.708 us; speedup vs baseline: 1.2381x; 1.2381x over previous
//
#include <hip/hip_runtime.h>
#include <hip/hip_bf16.h>
#include <math.h>

#define BATCH 512
#define FEAT  256
#define NCLS  100000
#define SCALE_ 32.0f
#define M0_    0.5f
#define MMIN_  0.25f

#define BN 32                        // classes per tile (100000 = 3125*32, no edge)
#define NT32 3125                    // exact tile count
#define NSLOTS 256                   // class-tile slots (stride)
#define NPART 256                    // partial slots per sample
#define K4CHUNK 16
#define NK4 (NPART / K4CHUNK)        // 16

#define LOG2E_ 1.44269504088896f
#define K2C_   (SCALE_ * LOG2E_)     // 46.166...; fixed softmax max (log2 domain)

typedef unsigned short u16;
typedef short s16x8 __attribute__((ext_vector_type(8)));
typedef float f32x4 __attribute__((ext_vector_type(4)));

// ---- static device scratch ----
__device__ u16   g_fbf16[BATCH * FEAT];    // normalized features, bf16
__device__ float g_norms[BATCH];
__device__ float g_dot[BATCH];             // raw f32 feat . W[label]
__device__ float g_wn2[BATCH];             // ||W[label]||^2 (f32)
__device__ float g_psum[NPART * BATCH];    // fixed-max partial sums
__device__ float g_qs[NK4 * BATCH];

__device__ __forceinline__ u16 f2b(float x) {
  union { float f; unsigned u; } v; v.f = x;
  unsigned r = v.u + 0x7FFFu + ((v.u >> 16) & 1u);   // RNE
  return (u16)(r >> 16);
}

// packed f32x2 -> bf16x2 (lo = a, hi = b)
__device__ __forceinline__ unsigned pkbf16(float a, float b) {
  unsigned r;
  asm("v_cvt_pk_bf16_f32 %0, %1, %2" : "=v"(r) : "v"(a), "v"(b));
  return r;
}

__device__ __forceinline__ float ex2(float x) {
  return __builtin_amdgcn_exp2f(x);
}

// K12 (merged k1a + k2c, data-independent halves):
// blocks 0..127: per-row feature norm -> NORMALIZED bf16 row + g_norms.
// blocks 128..255: raw f32 dot(feat_i, W[label_i]) and ||W[label_i]||^2;
//   label width (int32 vs int64) detected locally per wave.
__global__ void k12(const float* __restrict__ feat, const float* __restrict__ wmat,
                    const void* __restrict__ labels) {
  int b = blockIdx.x;
  int wid = threadIdx.x >> 6, lane = threadIdx.x & 63;
  if (b < 128) {
    int row = b * 4 + wid;
    float4 f = ((const float4*)(feat + row * FEAT))[lane];
    float ss = f.x * f.x + f.y * f.y + f.z * f.z + f.w * f.w;
    #pragma unroll
    for (int d = 1; d < 64; d <<= 1) ss += __shfl_xor(ss, d, 64);
    float nrm = sqrtf(ss);
    float inv = 1.0f / fmaxf(nrm, 1e-12f);
    ushort4 h;
    h.x = f2b(f.x * inv); h.y = f2b(f.y * inv);
    h.z = f2b(f.z * inv); h.w = f2b(f.w * inv);
    ((ushort4*)(g_fbf16 + row * FEAT))[lane] = h;
    if (lane == 0) g_norms[row] = nrm;
  } else {
    int i = (b - 128) * 4 + wid;
    const int* labw = (const int*)labels;
    int odd = 0;
    #pragma unroll
    for (int k = 0; k < 4; ++k) odd |= labw[2 * (k * 64 + lane) + 1];
    unsigned long long bl = __ballot(odd != 0);
    long long lab;
    if (bl != 0ULL) lab = (long long)((const int*)labels)[i];
    else            lab = ((const long long*)labels)[i];
    float4 a = ((const float4*)(feat + i * FEAT))[lane];
    float4 w = ((const float4*)(wmat + (size_t)lab * FEAT))[lane];
    float d  = a.x * w.x + a.y * w.y + a.z * w.z + a.w * w.w;
    float bb = w.x * w.x + w.y * w.y + w.z * w.z + w.w * w.w;
    #pragma unroll
    for (int t = 1; t < 64; t <<= 1) {
      d  += __shfl_xor(d, t, 64);
      bb += __shfl_xor(bb, t, 64);
    }
    if (lane == 0) { g_dot[i] = d; g_wn2[i] = bb; }
  }
}

// K3 (fused): R16 exactly (512 blocks x 256 threads, m=4, BN=32, 2x16 KB
// LDS dbuf -> 2 blocks/CU, sh-pair FETCH dedupe, split-FINISH, T5 setprio)
// with ONE schedule change: LOADC for tile t+2 is issued at the BOTTOM of
// iteration t (right after FINHALF1 frees v_), instead of LOADC(t+1) at the
// top of iteration t. Load-to-use distance grows from ~1 phase (~600 cy,
// exposing part of the ~900-cy HBM latency) to barrier+P0 (~1300+ cy):
// FINHALF0's vmcnt stall disappears. Single v_[8]; VGPR unchanged.

#define LOADC(TILE) do {                                                    \
    rowL_ = tid >> 4;                                                       \
    const float4* s0_ = (const float4*)(wmat + (size_t)((TILE) * BN + rowL_) * FEAT + (tid & 15) * 16);      \
    const float4* s1_ = (const float4*)(wmat + (size_t)((TILE) * BN + 16 + rowL_) * FEAT + (tid & 15) * 16); \
    v_[0] = s0_[0]; v_[1] = s0_[1]; v_[2] = s0_[2]; v_[3] = s0_[3];         \
    v_[4] = s1_[0]; v_[5] = s1_[1]; v_[6] = s1_[2]; v_[7] = s1_[3];         \
  } while (0)

#define FINHALF(NB, G, ROW) do {                                            \
    float ss_ = 0.0f;                                                       \
    _Pragma("unroll")                                                       \
    for (int k_ = 0; k_ < 4; ++k_) {                                        \
      float4 vv_ = v_[(G) * 4 + k_];                                        \
      ss_ += vv_.x * vv_.x + vv_.y * vv_.y + vv_.z * vv_.z + vv_.w * vv_.w; \
    }                                                                       \
    ss_ += __shfl_xor(ss_, 1, 64);                                          \
    ss_ += __shfl_xor(ss_, 2, 64);                                          \
    ss_ += __shfl_xor(ss_, 4, 64);                                          \
    ss_ += __shfl_xor(ss_, 8, 64);                                          \
    float inv_ = 1.0f / fmaxf(sqrtf(ss_), 1e-12f);                          \
    u16* dst_ = &Ws[NB][0] + (ROW) * FEAT;                                  \
    _Pragma("unroll")                                                       \
    for (int k_ = 0; k_ < 2; ++k_) {                                        \
      int jj_ = (tid & 15) * 2 + k_;                                        \
      float4 va_ = v_[(G) * 4 + 2 * k_], vb_ = v_[(G) * 4 + 2 * k_ + 1];    \
      int4 w4_;                                                             \
      w4_.x = (int)pkbf16(va_.x * inv_, va_.y * inv_);                      \
      w4_.y = (int)pkbf16(va_.z * inv_, va_.w * inv_);                      \
      w4_.z = (int)pkbf16(vb_.x * inv_, vb_.y * inv_);                      \
      w4_.w = (int)pkbf16(vb_.z * inv_, vb_.w * inv_);                      \
      *(int4*)(dst_ + ((jj_ ^ ((ROW) & 7)) * 8)) = w4_;                     \
    }                                                                       \
  } while (0)

#define PHASE(p8) do {                                                      \
    f32x4 acc[4];                                                           \
    _Pragma("unroll")                                                       \
    for (int m = 0; m < 4; ++m) acc[m] = f32x4{0.0f, 0.0f, 0.0f, 0.0f};     \
    const u16* wb = &Ws[buf][0];                                            \
    const int row_ = (p8) * 16 + s;                                         \
    __builtin_amdgcn_s_setprio(1);                                          \
    _Pragma("unroll")                                                       \
    for (int c = 0; c < 8; ++c) {                                           \
      int cc = c * 4 + q;                                                   \
      s16x8 wf = *(const s16x8*)(wb + row_ * FEAT + (cc ^ (row_ & 7)) * 8); \
      _Pragma("unroll")                                                     \
      for (int m = 0; m < 4; ++m)                                           \
        acc[m] = __builtin_amdgcn_mfma_f32_16x16x32_bf16(wf, fr[m][c], acc[m], 0, 0, 0); \
    }                                                                       \
    __builtin_amdgcn_s_setprio(0);                                          \
    _Pragma("unroll")                                                       \
    for (int m = 0; m < 4; ++m) {                                           \
      float sl = ex2(fmaf(acc[m][0], K2C_, -K2C_))                          \
               + ex2(fmaf(acc[m][1], K2C_, -K2C_))                          \
               + ex2(fmaf(acc[m][2], K2C_, -K2C_))                          \
               + ex2(fmaf(acc[m][3], K2C_, -K2C_));                         \
      S[m] += sl;                                                           \
    }                                                                       \
  } while (0)

__global__ __launch_bounds__(256, 1) void k3(const float* __restrict__ wmat) {
  __shared__ __align__(16) u16 Ws[2][BN * FEAT];   // 2 x 16 KB

  const int tid  = threadIdx.x;
  const int lane = tid & 63, wid = tid >> 6;       // 4 waves
  const int s = lane & 15, q = lane >> 4;
  const int bid = blockIdx.x;
  const int nslot = bid & 255;
  const int sh = bid >> 8;                         // sample half
  const int niter = ((NT32 - 1 - nslot) >> 8) + 1; // 13 (nslot<53) or 12

  int rowL_;
  float4 v_[8];

  // prologue: stage tile 0 into buf 0; issue tile 1's loads; fr loads overlap
  LOADC(nslot);
  FINHALF(0, 0, rowL_);
  FINHALF(0, 1, 16 + rowL_);
  LOADC(nslot + NSLOTS);               // tile 1 in flight across the barrier

  // feature fragments (B-operand): 64 samples per wave, register-resident.
  s16x8 fr[4][8];
  {
    const int srow = sh * 256 + wid * 64;
    #pragma unroll
    for (int m = 0; m < 4; ++m)
      #pragma unroll
      for (int c = 0; c < 8; ++c)
        fr[m][c] = *(const s16x8*)(g_fbf16 + (srow + m * 16 + s) * FEAT + c * 32 + q * 8);
  }

  float S[4] = {0.0f, 0.0f, 0.0f, 0.0f};

  __syncthreads();

  int buf = 0;
  for (int t = 0; t < niter; ++t) {
    const bool last = (t + 1 == niter);

    PHASE(0);
    if (!last) FINHALF(buf ^ 1, 0, rowL_);
    PHASE(1);
    if (!last) FINHALF(buf ^ 1, 1, 16 + rowL_);
    if (t + 2 < niter) LOADC(nslot + (t + 2) * NSLOTS);
    __syncthreads();
    buf ^= 1;
  }

  // cross-lane sum (once): combine the 4 q-groups per sample.
  #pragma unroll
  for (int m = 0; m < 4; ++m) {
    S[m] += __shfl_xor(S[m], 16, 64);
    S[m] += __shfl_xor(S[m], 32, 64);
  }

  if (lane < 16) {
    #pragma unroll
    for (int m = 0; m < 4; ++m) {
      int smp = sh * 256 + wid * 64 + m * 16 + lane;
      g_psum[nslot * BATCH + smp] = S[m];
    }
  }
}

// K4a: sum 16 of the 256 partial slots per sample per block (coalesced).
__global__ __launch_bounds__(512) void k4a() {
  int i = threadIdx.x;   // sample
  int b = blockIdx.x;    // chunk of partial slots
  float S = 0.0f;
  #pragma unroll 4
  for (int p = b * K4CHUNK; p < b * K4CHUNK + K4CHUNK; ++p)
    S += g_psum[p * BATCH + i];
  g_qs[b * BATCH + i] = S;
}

// K4b: chunk sum + margins (min/max of norms) + target-logit fixup +
// weighted mean. Fixed max K2C_ (log2 domain): lse = 32 + ln(S2).
__global__ void k4b(const float* __restrict__ wts, float* __restrict__ out) {
  int i = threadIdx.x;  // 512
  float S = 0.0f;
  #pragma unroll
  for (int t = 0; t < NK4; ++t) S += g_qs[t * BATCH + i];

  float n = g_norms[i];
  __shared__ float smin[512], smax[512];
  smin[i] = n; smax[i] = n;
  __syncthreads();
  for (int st = 256; st > 0; st >>= 1) {
    if (i < st) {
      smin[i] = fminf(smin[i], smin[i + st]);
      smax[i] = fmaxf(smax[i], smax[i + st]);
    }
    __syncthreads();
  }
  float lo = smin[0], hi = smax[0];
  float denom = fmaxf(hi - lo, 1e-8f);
  float mg = MMIN_ + (M0_ - MMIN_) * (n - lo) / denom;
  mg = fminf(fmaxf(mg, MMIN_), M0_);

  const float CLIP = 1.0f - 1e-7f;
  float wn = fmaxf(sqrtf(g_wn2[i]), 1e-12f);
  float ct = g_dot[i] / (fmaxf(n, 1e-12f) * wn);
  ct = fminf(fmaxf(ct, -CLIP), CLIP);

  float sint = sqrtf(fmaxf(0.0f, 1.0f - ct * ct));
  float cosm = ct * cosf(mg) - sint * sinf(mg);
  float b_old = K2C_ * ct;            // log2-domain target logits
  float b_new = K2C_ * cosm;
  float S2 = S - ex2(b_old - K2C_) + ex2(b_new - K2C_);
  float lse = 32.0f + logf(S2);       // natural-log lse (K2C_*ln2 = 32)
  float contrib = (lse - SCALE_ * cosm) * wts[i];
  __shared__ float sred[512];
  sred[i] = contrib;
  __syncthreads();
  for (int st = 256; st > 0; st >>= 1) {
    if (i < st) sred[i] += sred[i + st];
    __syncthreads();
  }
  if (i == 0) out[0] = sred[0] * (1.0f / (float)BATCH);
}

extern "C" void kernel_launch(void* const* d_in, const int* in_sizes, int n_in,
                              void* d_out, int out_size, void* d_ws, size_t ws_size,
                              hipStream_t stream) {
  const float* feat = (const float*)d_in[0];
  const float* wmat = (const float*)d_in[1];
  const float* wts  = (const float*)d_in[2];
  const void*  labs = d_in[3];
  float* out = (float*)d_out;

  hipLaunchKernelGGL(k12, dim3(256), dim3(256), 0, stream, feat, wmat, labs);
  hipLaunchKernelGGL(k3,  dim3(512), dim3(256), 0, stream, wmat);
  hipLaunchKernelGGL(k4a, dim3(NK4), dim3(512), 0, stream);
  hipLaunchKernelGGL(k4b, dim3(1), dim3(512), 0, stream, wts, out);
}